// Round 1
// baseline (151.976 us; speedup 1.0000x reference)
//
#include <hip/hip_runtime.h>

typedef float f32x4 __attribute__((ext_vector_type(4)));
typedef short bf16x8 __attribute__((ext_vector_type(8)));

__device__ __forceinline__ short f2bf(float f) {
    union { float f; unsigned u; } c; c.f = f;
    unsigned r = (c.u + 0x7fffu + ((c.u >> 16) & 1u)) >> 16;
    return (short)r;
}

#define XT_STRIDE 296   // bf16 elems, row stride of x tile (276 used + pad)
#define YL_STRIDE 136   // bf16 elems, row stride of y tile (128 used + pad)
#define ZL_STRIDE 68    // f32 elems, row stride of z tile (64 used + pad)
#define LDS_BYTES 56320

__global__ __launch_bounds__(384) void net_fused(
    const float* __restrict__ state,
    const float* __restrict__ myp,  const float* __restrict__ hisp,
    const float* __restrict__ w1a,  const float* __restrict__ b1a,
    const float* __restrict__ w2a,  const float* __restrict__ b2a,
    const float* __restrict__ w1v,  const float* __restrict__ b1v,
    const float* __restrict__ w2v,  const float* __restrict__ b2v,
    float* __restrict__ out, int Btot)
{
    __shared__ __align__(16) unsigned char smem[LDS_BYTES];
    short* xt   = (short*)smem;                 // [64][296] bf16 features
    float* zl   = (float*)smem;                 // [64][68] f32 (aliases xt, used after GEMM1)
    short* yl   = (short*)(smem + 37888);       // [64][136] bf16 hidden act
    float* valp = (float*)(smem + 55296);       // [4][64] val partials

    const int tid  = threadIdx.x;
    const int w    = tid >> 6;        // wave 0..5
    const int l    = tid & 63;        // lane
    const int lrow = l & 15;
    const int lk   = l >> 4;
    const int bg0  = blockIdx.x * 64;

    // ---- phase 0: zero x & y LDS regions (covers K-padding) ----
    for (int i = tid; i < 13824; i += 384) ((unsigned*)smem)[i] = 0u;
    __syncthreads();

    // ---- phase 1: conv features (wave = (p,j) pair, lane = batch row) ----
    {
        constexpr int M8[8][8] = {
            {0,1,2,3,3,2,1,0},
            {1,4,5,6,6,5,4,1},
            {2,5,7,8,8,7,5,2},
            {3,6,8,9,9,8,6,3},
            {3,6,8,9,9,8,6,3},
            {2,5,7,8,8,7,5,2},
            {1,4,5,6,6,5,4,1},
            {0,1,2,3,3,2,1,0}};
        const int b = l;
        const int p = (w >= 3) ? 1 : 0;
        const int j = (w >= 3) ? (w - 3) : w;
        const float* prmsrc = (p == 0 ? myp : hisp) + j * 10;
        float prm[10];
        #pragma unroll
        for (int i = 0; i < 10; i++) prm[i] = prmsrc[i];
        float racc[8], cacc[8], macc[15], aacc[15];
        #pragma unroll
        for (int i = 0; i < 8; i++) { racc[i] = 0.f; cacc[i] = 0.f; }
        #pragma unroll
        for (int i = 0; i < 15; i++) { macc[i] = 0.f; aacc[i] = 0.f; }
        const float* S = state + ((size_t)(bg0 + b) * 2 + p) * 64;
        #pragma unroll
        for (int x = 0; x < 8; x++) {
            f32x4 lo = *(const f32x4*)(S + x * 8);
            f32x4 hi = *(const f32x4*)(S + x * 8 + 4);
            #pragma unroll
            for (int y = 0; y < 8; y++) {
                float s = (y < 4) ? lo[y] : hi[y - 4];
                float t = s * prm[M8[x][y]];
                racc[x] += t;
                cacc[y] += t;                       // D symmetric -> col dot = col sum of P
                macc[(y >= x) ? (y - x) : (x - y + 7)] += t;
                aacc[x + y] += t;
            }
        }
        short* xr = xt + b * XT_STRIDE;
        #pragma unroll
        for (int i = 0; i < 8; i++)  xr[(j * 8 + i) * 2 + p]        = f2bf(fmaxf(racc[i], 0.f));
        #pragma unroll
        for (int i = 0; i < 8; i++)  xr[48 + (j * 8 + i) * 2 + p]   = f2bf(fmaxf(cacc[i], 0.f));
        #pragma unroll
        for (int k = 0; k < 15; k++) xr[96 + (j * 15 + k) * 2 + p]  = f2bf(fmaxf(macc[k], 0.f));
        #pragma unroll
        for (int k = 0; k < 15; k++) xr[186 + (j * 15 + k) * 2 + p] = f2bf(fmaxf(aacc[k], 0.f));
    }
    __syncthreads();

    // ---- phase 2: GEMM1  x[64,288] @ W1[288,176] (N: 0..99 act, 112..175 val) ----
    const int nnt = (w < 5) ? 2 : 1;
    const int ntArr[2] = { w, w + 6 };
    f32x4 acc[2][4];
    {
        bf16x8 bf[2][9];
        for (int ni = 0; ni < nnt; ni++) {
            const int nt = ntArr[ni];
            const int n  = nt * 16 + lrow;
            const float* src; bool valid;
            if (n < 100)       { src = w1a + (size_t)n * 276;          valid = true;  }
            else if (n >= 112) { src = w1v + (size_t)(n - 112) * 276;  valid = true;  }
            else               { src = w1a;                            valid = false; }
            #pragma unroll
            for (int kc = 0; kc < 9; kc++) {
                const int k0 = kc * 32 + lk * 8;
                bf16x8 r;
                if (valid && (k0 + 8 <= 276)) {
                    f32x4 lo = *(const f32x4*)(src + k0);
                    f32x4 hi = *(const f32x4*)(src + k0 + 4);
                    #pragma unroll
                    for (int e = 0; e < 4; e++) { r[e] = f2bf(lo[e]); r[4 + e] = f2bf(hi[e]); }
                } else {
                    #pragma unroll
                    for (int e = 0; e < 8; e++) {
                        int k = k0 + e;
                        bool ok = valid && (k < 276);
                        float v = src[ok ? k : 0];
                        r[e] = f2bf(ok ? v : 0.f);
                    }
                }
                bf[ni][kc] = r;
            }
        }
        #pragma unroll
        for (int ni = 0; ni < 2; ni++)
            #pragma unroll
            for (int mt = 0; mt < 4; mt++)
                acc[ni][mt] = (f32x4){0.f, 0.f, 0.f, 0.f};
        for (int mt = 0; mt < 4; mt++) {
            bf16x8 a[9];
            #pragma unroll
            for (int kc = 0; kc < 9; kc++)
                a[kc] = *(const bf16x8*)(xt + (mt * 16 + lrow) * XT_STRIDE + kc * 32 + lk * 8);
            for (int ni = 0; ni < nnt; ni++) {
                #pragma unroll
                for (int kc = 0; kc < 9; kc++)
                    acc[ni][mt] = __builtin_amdgcn_mfma_f32_16x16x32_bf16(a[kc], bf[ni][kc], acc[ni][mt], 0, 0, 0);
            }
        }
    }
    // epilogue: act tiles -> y LDS (bf16); val tiles -> reduce -> valp
    for (int ni = 0; ni < nnt; ni++) {
        const int nt  = ntArr[ni];
        const int col = nt * 16 + lrow;
        if (nt <= 6) {
            float bias = (col < 100) ? b1a[col] : 0.f;
            #pragma unroll
            for (int mt = 0; mt < 4; mt++)
                #pragma unroll
                for (int r = 0; r < 4; r++) {
                    float v = fmaxf(acc[ni][mt][r] + bias, 0.f);
                    yl[(mt * 16 + lk * 4 + r) * YL_STRIDE + col] = f2bf(v);
                }
        } else {
            const int nv = col - 112;
            float bias = b1v[nv];
            float wv   = w2v[nv];
            #pragma unroll
            for (int mt = 0; mt < 4; mt++)
                #pragma unroll
                for (int r = 0; r < 4; r++) {
                    float v = fmaxf(acc[ni][mt][r] + bias, 0.f) * wv;
                    v += __shfl_xor(v, 1); v += __shfl_xor(v, 2);
                    v += __shfl_xor(v, 4); v += __shfl_xor(v, 8);
                    if (lrow == 0) valp[(nt - 7) * 64 + mt * 16 + lk * 4 + r] = v;
                }
        }
    }
    __syncthreads();

    // ---- phase 3: GEMM2  y[64,128] @ W2[128,64] (waves 0..3); wave 4: tanh(val) ----
    if (w < 4) {
        bf16x8 b2[4];
        const int n = w * 16 + lrow;
        const float* src2 = w2a + (size_t)n * 100;
        #pragma unroll
        for (int kc = 0; kc < 4; kc++) {
            const int k0 = kc * 32 + lk * 8;
            bf16x8 r;
            if (k0 + 8 <= 100) {
                f32x4 lo = *(const f32x4*)(src2 + k0);
                f32x4 hi = *(const f32x4*)(src2 + k0 + 4);
                #pragma unroll
                for (int e = 0; e < 4; e++) { r[e] = f2bf(lo[e]); r[4 + e] = f2bf(hi[e]); }
            } else {
                #pragma unroll
                for (int e = 0; e < 8; e++) {
                    int k = k0 + e;
                    bool ok = (k < 100);
                    float v = src2[ok ? k : 0];
                    r[e] = f2bf(ok ? v : 0.f);
                }
            }
            b2[kc] = r;
        }
        f32x4 acc2[4];
        #pragma unroll
        for (int mt = 0; mt < 4; mt++) acc2[mt] = (f32x4){0.f, 0.f, 0.f, 0.f};
        #pragma unroll
        for (int mt = 0; mt < 4; mt++) {
            #pragma unroll
            for (int kc = 0; kc < 4; kc++) {
                bf16x8 a2 = *(const bf16x8*)(yl + (mt * 16 + lrow) * YL_STRIDE + kc * 32 + lk * 8);
                acc2[mt] = __builtin_amdgcn_mfma_f32_16x16x32_bf16(a2, b2[kc], acc2[mt], 0, 0, 0);
            }
        }
        float bias2 = b2a[w * 16 + lrow];
        #pragma unroll
        for (int mt = 0; mt < 4; mt++)
            #pragma unroll
            for (int r = 0; r < 4; r++)
                zl[(mt * 16 + lk * 4 + r) * ZL_STRIDE + w * 16 + lrow] = acc2[mt][r] + bias2;
    } else if (w == 4) {
        float v = valp[l] + valp[64 + l] + valp[128 + l] + valp[192 + l] + b2v[0];
        out[(size_t)Btot * 64 + bg0 + l] = tanhf(v);
    }
    __syncthreads();

    // ---- phase 4: log-softmax over 64 cols, 4 lanes per row ----
    if (w < 4) {
        const int rl = l >> 2, q = l & 3;
        const int row = w * 16 + rl;
        const float* zr = zl + row * ZL_STRIDE + q * 16;
        float v[16];
        float m = -1e30f;
        #pragma unroll
        for (int c = 0; c < 16; c++) { v[c] = zr[c]; m = fmaxf(m, v[c]); }
        m = fmaxf(m, __shfl_xor(m, 1));
        m = fmaxf(m, __shfl_xor(m, 2));
        float s = 0.f;
        #pragma unroll
        for (int c = 0; c < 16; c++) s += __expf(v[c] - m);
        s += __shfl_xor(s, 1);
        s += __shfl_xor(s, 2);
        float lsm = m + __logf(s);
        float* o = out + (size_t)(bg0 + row) * 64 + q * 16;
        #pragma unroll
        for (int c = 0; c < 16; c++) o[c] = v[c] - lsm;
    }
}

extern "C" void kernel_launch(void* const* d_in, const int* in_sizes, int n_in,
                              void* d_out, int out_size, void* d_ws, size_t ws_size,
                              hipStream_t stream) {
    const float* state = (const float*)d_in[0];
    const float* myp   = (const float*)d_in[1];
    const float* hisp  = (const float*)d_in[2];
    const float* w1a   = (const float*)d_in[3];
    const float* b1a   = (const float*)d_in[4];
    const float* w2a   = (const float*)d_in[5];
    const float* b2a   = (const float*)d_in[6];
    const float* w1v   = (const float*)d_in[7];
    const float* b1v   = (const float*)d_in[8];
    const float* w2v   = (const float*)d_in[9];
    const float* b2v   = (const float*)d_in[10];
    float* out = (float*)d_out;
    const int Btot = in_sizes[0] / 128;          // (B,2,8,8)
    const int blocks = Btot / 64;
    net_fused<<<dim3(blocks), dim3(384), 0, stream>>>(
        state, myp, hisp, w1a, b1a, w2a, b2a, w1v, b1v, w2v, b2v, out, Btot);
}

// Round 3
// 131.749 us; speedup vs baseline: 1.1535x; 1.1535x over previous
//
#include <hip/hip_runtime.h>

typedef float f32x4 __attribute__((ext_vector_type(4)));
typedef short bf16x8 __attribute__((ext_vector_type(8)));

__device__ __forceinline__ short f2bf(float f) {
    union { float f; unsigned u; } c; c.f = f;
    unsigned r = (c.u + 0x7fffu + ((c.u >> 16) & 1u)) >> 16;
    return (short)r;
}

#define XT_STRIDE 296   // bf16 elems, row stride of x tile (276 used + pad)
#define YL_STRIDE 136   // bf16 elems, row stride of y tile (128 used + pad)
#define ZL_STRIDE 68    // f32 elems, row stride of z tile (64 used + pad)
#define LDS_BYTES 56320
#define MPB 2           // 64-row groups per block

#define W1_FRAG_SHORTS (99*64*8)    // 11 n-tiles x 9 k-chunks
#define W2_FRAG_SHORTS (16*64*8)    // 4 n-tiles x 4 k-chunks
#define WS_SHORTS (W1_FRAG_SHORTS + W2_FRAG_SHORTS)   // 58880 shorts = 117760 B

// ---- one-time weight -> bf16 MFMA-fragment layout ----
__global__ __launch_bounds__(256) void prep_weights(
    const float* __restrict__ w1a, const float* __restrict__ w1v,
    const float* __restrict__ w2a, short* __restrict__ ws)
{
    int i = blockIdx.x * 256 + threadIdx.x;
    if (i < W1_FRAG_SHORTS) {
        int e = i & 7, lane = (i >> 3) & 63, tc = i >> 9;   // tc = nt*9+kc
        int nt = tc / 9, kc = tc % 9;
        int n = nt * 16 + (lane & 15);
        int k = kc * 32 + (lane >> 4) * 8 + e;
        float v = 0.f;
        if (k < 276) {
            if (n < 100)                 v = w1a[n * 276 + k];
            else if (n >= 112 && n < 176) v = w1v[(n - 112) * 276 + k];
        }
        ws[i] = f2bf(v);
    } else if (i < WS_SHORTS) {
        int j = i - W1_FRAG_SHORTS;
        int e = j & 7, lane = (j >> 3) & 63, tc = j >> 9;   // tc = nt*4+kc
        int n = (tc >> 2) * 16 + (lane & 15);
        int k = (tc & 3) * 32 + (lane >> 4) * 8 + e;
        float v = (k < 100) ? w2a[n * 100 + k] : 0.f;
        ws[i] = f2bf(v);
    }
}

template<bool USE_WS>
__global__ __launch_bounds__(384) void net_fused(
    const float* __restrict__ state,
    const float* __restrict__ myp,  const float* __restrict__ hisp,
    const float* __restrict__ w1a,  const float* __restrict__ b1a,
    const float* __restrict__ w2a,  const float* __restrict__ b2a,
    const float* __restrict__ w1v,  const float* __restrict__ b1v,
    const float* __restrict__ w2v,  const float* __restrict__ b2v,
    const short* __restrict__ wsf,
    float* __restrict__ out, int Btot)
{
    __shared__ __align__(16) unsigned char smem[LDS_BYTES];
    short* xt   = (short*)smem;                 // [64][296] bf16 features
    float* zl   = (float*)smem;                 // [64][68] f32 (ALIASES xt rows 0..29!)
    short* yl   = (short*)(smem + 37888);       // [64][136] bf16 hidden act
    float* valp = (float*)(smem + 55296);       // [4][64] val partials

    const int tid  = threadIdx.x;
    const int w    = tid >> 6;        // wave 0..5
    const int l    = tid & 63;        // lane
    const int lrow = l & 15;
    const int lk   = l >> 4;

    // ---- zero x & y LDS (covers all K/N padding) ----
    for (int i = tid; i < 13824; i += 384) ((unsigned*)smem)[i] = 0u;

    // ---- hoisted per-block loads: weight fragments, conv params, biases ----
    const int nnt = (w < 5) ? 2 : 1;
    const int ntArr[2] = { w, w + 6 };
    bf16x8 bf[2][9];
    for (int ni = 0; ni < nnt; ni++) {
        const int nt = ntArr[ni];
        if (USE_WS) {
            #pragma unroll
            for (int kc = 0; kc < 9; kc++)
                bf[ni][kc] = *(const bf16x8*)(wsf + ((nt * 9 + kc) * 64 + l) * 8);
        } else {
            const int n = nt * 16 + lrow;
            const float* src; bool valid;
            if (n < 100)       { src = w1a + (size_t)n * 276;          valid = true;  }
            else if (n >= 112) { src = w1v + (size_t)(n - 112) * 276;  valid = true;  }
            else               { src = w1a;                            valid = false; }
            #pragma unroll
            for (int kc = 0; kc < 9; kc++) {
                const int k0 = kc * 32 + lk * 8;
                bf16x8 r;
                #pragma unroll
                for (int e = 0; e < 8; e++) {
                    int k = k0 + e;
                    bool ok = valid && (k < 276);
                    r[e] = f2bf(ok ? src[ok ? k : 0] : 0.f);
                }
                bf[ni][kc] = r;
            }
        }
    }
    bf16x8 b2f[4];
    float bias2 = 0.f;
    if (w < 4) {
        if (USE_WS) {
            #pragma unroll
            for (int kc = 0; kc < 4; kc++)
                b2f[kc] = *(const bf16x8*)(wsf + W1_FRAG_SHORTS + ((w * 4 + kc) * 64 + l) * 8);
        } else {
            const int n = w * 16 + lrow;
            const float* src2 = w2a + (size_t)n * 100;
            #pragma unroll
            for (int kc = 0; kc < 4; kc++) {
                const int k0 = kc * 32 + lk * 8;
                bf16x8 r;
                #pragma unroll
                for (int e = 0; e < 8; e++) {
                    int k = k0 + e;
                    r[e] = f2bf((k < 100) ? src2[k] : 0.f);
                }
                b2f[kc] = r;
            }
        }
        bias2 = b2a[w * 16 + lrow];
    }
    // epilogue constants for GEMM1
    float ep_bias[2] = {0.f, 0.f}, ep_wv[2] = {0.f, 0.f};
    for (int ni = 0; ni < nnt; ni++) {
        const int col = ntArr[ni] * 16 + lrow;
        if (ntArr[ni] <= 6) ep_bias[ni] = (col < 100) ? b1a[col] : 0.f;
        else { ep_bias[ni] = b1v[col - 112]; ep_wv[ni] = w2v[col - 112]; }
    }
    const float b2v0 = b2v[0];
    // conv params
    const int cp = (w >= 3) ? 1 : 0;
    const int cj = (w >= 3) ? (w - 3) : w;
    float prm[10];
    {
        const float* prmsrc = (cp == 0 ? myp : hisp) + cj * 10;
        #pragma unroll
        for (int i = 0; i < 10; i++) prm[i] = prmsrc[i];
    }
    __syncthreads();

    for (int g = 0; g < MPB; ++g) {
        const int bg0 = (blockIdx.x * MPB + g) * 64;
        if (bg0 >= Btot) break;

        // ---- phase 1: conv features (wave = (p,j) pair, lane = batch row) ----
        {
            constexpr int M8[8][8] = {
                {0,1,2,3,3,2,1,0},
                {1,4,5,6,6,5,4,1},
                {2,5,7,8,8,7,5,2},
                {3,6,8,9,9,8,6,3},
                {3,6,8,9,9,8,6,3},
                {2,5,7,8,8,7,5,2},
                {1,4,5,6,6,5,4,1},
                {0,1,2,3,3,2,1,0}};
            float racc[8], cacc[8], macc[15], aacc[15];
            #pragma unroll
            for (int i = 0; i < 8; i++) { racc[i] = 0.f; cacc[i] = 0.f; }
            #pragma unroll
            for (int i = 0; i < 15; i++) { macc[i] = 0.f; aacc[i] = 0.f; }
            const float* S = state + ((size_t)(bg0 + l) * 2 + cp) * 64;
            #pragma unroll
            for (int x = 0; x < 8; x++) {
                f32x4 lo = *(const f32x4*)(S + x * 8);
                f32x4 hi = *(const f32x4*)(S + x * 8 + 4);
                #pragma unroll
                for (int y = 0; y < 8; y++) {
                    float s = (y < 4) ? lo[y] : hi[y - 4];
                    float t = s * prm[M8[x][y]];
                    racc[x] += t;
                    cacc[y] += t;
                    macc[(y >= x) ? (y - x) : (x - y + 7)] += t;
                    aacc[x + y] += t;
                }
            }
            short* xr = xt + l * XT_STRIDE;
            // re-zero K-pad cols 276..287 (clobbered by zl aliasing in prev group)
            if (w == 0) {
                unsigned* xp = (unsigned*)(xr + 276);
                xp[0] = 0u; xp[1] = 0u; xp[2] = 0u;
                xp[3] = 0u; xp[4] = 0u; xp[5] = 0u;
            }
            #pragma unroll
            for (int i = 0; i < 8; i++)  xr[(cj * 8 + i) * 2 + cp]        = f2bf(fmaxf(racc[i], 0.f));
            #pragma unroll
            for (int i = 0; i < 8; i++)  xr[48 + (cj * 8 + i) * 2 + cp]   = f2bf(fmaxf(cacc[i], 0.f));
            #pragma unroll
            for (int k = 0; k < 15; k++) xr[96 + (cj * 15 + k) * 2 + cp]  = f2bf(fmaxf(macc[k], 0.f));
            #pragma unroll
            for (int k = 0; k < 15; k++) xr[186 + (cj * 15 + k) * 2 + cp] = f2bf(fmaxf(aacc[k], 0.f));
        }
        __syncthreads();

        // ---- phase 2: GEMM1  x[64,288] @ W1[288,176] ----
        f32x4 acc[2][4];
        #pragma unroll
        for (int ni = 0; ni < 2; ni++)
            #pragma unroll
            for (int mt = 0; mt < 4; mt++)
                acc[ni][mt] = (f32x4){0.f, 0.f, 0.f, 0.f};
        for (int mt = 0; mt < 4; mt++) {
            bf16x8 a[9];
            #pragma unroll
            for (int kc = 0; kc < 9; kc++)
                a[kc] = *(const bf16x8*)(xt + (mt * 16 + lrow) * XT_STRIDE + kc * 32 + lk * 8);
            for (int ni = 0; ni < nnt; ni++) {
                #pragma unroll
                for (int kc = 0; kc < 9; kc++)
                    acc[ni][mt] = __builtin_amdgcn_mfma_f32_16x16x32_bf16(a[kc], bf[ni][kc], acc[ni][mt], 0, 0, 0);
            }
        }
        // epilogue: act tiles -> y LDS (bf16); val tiles -> reduce -> valp
        for (int ni = 0; ni < nnt; ni++) {
            const int nt  = ntArr[ni];
            const int col = nt * 16 + lrow;
            if (nt <= 6) {
                #pragma unroll
                for (int mt = 0; mt < 4; mt++)
                    #pragma unroll
                    for (int r = 0; r < 4; r++) {
                        float v = fmaxf(acc[ni][mt][r] + ep_bias[ni], 0.f);
                        yl[(mt * 16 + lk * 4 + r) * YL_STRIDE + col] = f2bf(v);
                    }
            } else {
                #pragma unroll
                for (int mt = 0; mt < 4; mt++)
                    #pragma unroll
                    for (int r = 0; r < 4; r++) {
                        float v = fmaxf(acc[ni][mt][r] + ep_bias[ni], 0.f) * ep_wv[ni];
                        v += __shfl_xor(v, 1); v += __shfl_xor(v, 2);
                        v += __shfl_xor(v, 4); v += __shfl_xor(v, 8);
                        if (lrow == 0) valp[(nt - 7) * 64 + mt * 16 + lk * 4 + r] = v;
                    }
            }
        }
        __syncthreads();

        // ---- phase 3: GEMM2 (waves 0..3); wave 4: tanh(val) ----
        if (w < 4) {
            f32x4 acc2[4];
            #pragma unroll
            for (int mt = 0; mt < 4; mt++) acc2[mt] = (f32x4){0.f, 0.f, 0.f, 0.f};
            #pragma unroll
            for (int mt = 0; mt < 4; mt++) {
                #pragma unroll
                for (int kc = 0; kc < 4; kc++) {
                    bf16x8 a2 = *(const bf16x8*)(yl + (mt * 16 + lrow) * YL_STRIDE + kc * 32 + lk * 8);
                    acc2[mt] = __builtin_amdgcn_mfma_f32_16x16x32_bf16(a2, b2f[kc], acc2[mt], 0, 0, 0);
                }
            }
            #pragma unroll
            for (int mt = 0; mt < 4; mt++)
                #pragma unroll
                for (int r = 0; r < 4; r++)
                    zl[(mt * 16 + lk * 4 + r) * ZL_STRIDE + w * 16 + lrow] = acc2[mt][r] + bias2;
        } else if (w == 4) {
            float v = valp[l] + valp[64 + l] + valp[128 + l] + valp[192 + l] + b2v0;
            out[(size_t)Btot * 64 + bg0 + l] = tanhf(v);
        }
        __syncthreads();

        // ---- phase 4: log-softmax, lane (rl,q): q owns cols {c16*16+q*4 .. +3} ----
        if (w < 4) {
            const int rl = l >> 2, q = l & 3;
            const int row = w * 16 + rl;
            const float* zr = zl + row * ZL_STRIDE;
            f32x4 v[4];
            float m = -1e30f;
            #pragma unroll
            for (int c16 = 0; c16 < 4; c16++) {
                v[c16] = *(const f32x4*)(zr + c16 * 16 + q * 4);
                m = fmaxf(m, fmaxf(fmaxf(v[c16][0], v[c16][1]), fmaxf(v[c16][2], v[c16][3])));
            }
            m = fmaxf(m, __shfl_xor(m, 1));
            m = fmaxf(m, __shfl_xor(m, 2));
            float s = 0.f;
            #pragma unroll
            for (int c16 = 0; c16 < 4; c16++)
                #pragma unroll
                for (int e = 0; e < 4; e++) s += __expf(v[c16][e] - m);
            s += __shfl_xor(s, 1);
            s += __shfl_xor(s, 2);
            const float lsm = m + __logf(s);
            float* o = out + (size_t)(bg0 + row) * 64;
            #pragma unroll
            for (int c16 = 0; c16 < 4; c16++) {
                f32x4 ov;
                #pragma unroll
                for (int e = 0; e < 4; e++) ov[e] = v[c16][e] - lsm;
                *(f32x4*)(o + c16 * 16 + q * 4) = ov;
            }
        }
        __syncthreads();   // zl/xt/yl reused by next group
    }
}

extern "C" void kernel_launch(void* const* d_in, const int* in_sizes, int n_in,
                              void* d_out, int out_size, void* d_ws, size_t ws_size,
                              hipStream_t stream) {
    const float* state = (const float*)d_in[0];
    const float* myp   = (const float*)d_in[1];
    const float* hisp  = (const float*)d_in[2];
    const float* w1a   = (const float*)d_in[3];
    const float* b1a   = (const float*)d_in[4];
    const float* w2a   = (const float*)d_in[5];
    const float* b2a   = (const float*)d_in[6];
    const float* w1v   = (const float*)d_in[7];
    const float* b1v   = (const float*)d_in[8];
    const float* w2v   = (const float*)d_in[9];
    const float* b2v   = (const float*)d_in[10];
    float* out = (float*)d_out;
    const int Btot = in_sizes[0] / 128;          // (B,2,8,8)
    const int blocks = (Btot + 64 * MPB - 1) / (64 * MPB);
    const bool use_ws = ws_size >= (size_t)WS_SHORTS * sizeof(short);
    if (use_ws) {
        short* ws = (short*)d_ws;
        prep_weights<<<dim3((WS_SHORTS + 255) / 256), dim3(256), 0, stream>>>(w1a, w1v, w2a, ws);
        net_fused<true><<<dim3(blocks), dim3(384), 0, stream>>>(
            state, myp, hisp, w1a, b1a, w2a, b2a, w1v, b1v, w2v, b2v, ws, out, Btot);
    } else {
        net_fused<false><<<dim3(blocks), dim3(384), 0, stream>>>(
            state, myp, hisp, w1a, b1a, w2a, b2a, w1v, b1v, w2v, b2v, (const short*)nullptr, out, Btot);
    }
}